// Round 7
// baseline (660.583 us; speedup 1.0000x reference)
//
#include <hip/hip_runtime.h>

// ============================================================================
// XModel_66795331387584: complex phase-feature ridge loss on MI355X (gfx950)
//
// loss = mean_{a,z} sum_d | num_MN/den_MN - num_X/den_X |^2
// den path: split-bf16 (hi+lo), fp32 out (tail-dominated 1/|den|^2).
// gamma_X via 1-term Neumann: gx = (K12 - K@K12/reg)/reg (rel err 4e-6).
//
// R7: k_gemm1 epilogue reads K12^T as hi/lo bf16 planes (coalesced; the fp32
// K12[j*2000+z] scatter was ~256 MB effective HBM traffic). k_pre phases
// branch vectorized (8 j/thread, bf16x8 stores). Kbf/K12T/K12TL overlay the
// chunk region (dead after k_gemm1): fixed 48 MB + 152 MB chunk @ ZC=1024.
// ============================================================================

typedef __bf16 bf16;
typedef __bf16 bf16x8 __attribute__((ext_vector_type(8)));
typedef float f32x4 __attribute__((ext_vector_type(4)));

#define AS1 __attribute__((address_space(1)))
#define AS3 __attribute__((address_space(3)))

__device__ __forceinline__ void async16(const void* g, void* l) {
  __builtin_amdgcn_global_load_lds((AS1 const unsigned int*)g,
                                   (AS3 unsigned int*)l, 16, 0, 0);
}

// ------------------- k_pre: phases + converts + out zero --------------------
// bid <1024: phases (a=bid, 8 j/thread) | [1024,3072): K11->bf16 |
// [3072,4096): K12^T -> hi/lo bf16
__global__ __launch_bounds__(256) void k_pre(
    const float* __restrict__ al, const float* __restrict__ Nm,
    const float* __restrict__ Xm, const float* __restrict__ K11,
    const float* __restrict__ K12, bf16* __restrict__ AphH,
    bf16* __restrict__ AphL, bf16* __restrict__ Kbf,
    bf16* __restrict__ K12T, bf16* __restrict__ K12TL,
    float* __restrict__ out) {
  __shared__ float t[64][65];
  const int bid = blockIdx.x, tid = threadIdx.x;
  if (bid < 1024) {
    if (bid == 0 && tid == 0) out[0] = 0.f;
    const size_t PA = (size_t)1024 * 2048;
    int a = bid;
    int j0 = tid * 8;
    float vc[4][8];
    if (a < 1000) {
      const float4* A4 = (const float4*)al;
      const float4* N4 = (const float4*)Nm;
      const float4* X4 = (const float4*)Xm;
      float4 a0 = A4[a * 2], a1 = A4[a * 2 + 1];
#pragma unroll
      for (int e = 0; e < 8; ++e) {
        int j = j0 + e;
        if (j < 2000) {
          float4 n0 = N4[j * 2], n1 = N4[j * 2 + 1];
          float4 x0 = X4[j * 2], x1 = X4[j * 2 + 1];
          float pn = a0.x * n0.x + a0.y * n0.y + a0.z * n0.z + a0.w * n0.w +
                     a1.x * n1.x + a1.y * n1.y + a1.z * n1.z + a1.w * n1.w;
          float px = a0.x * x0.x + a0.y * x0.y + a0.z * x0.z + a0.w * x0.w +
                     a1.x * x1.x + a1.y * x1.y + a1.z * x1.z + a1.w * x1.w;
          __sincosf(pn, &vc[1][e], &vc[0][e]);
          __sincosf(px, &vc[3][e], &vc[2][e]);
        } else {
          vc[0][e] = vc[1][e] = vc[2][e] = vc[3][e] = 0.f;
        }
      }
    } else {
#pragma unroll
      for (int p = 0; p < 4; ++p)
#pragma unroll
        for (int e = 0; e < 8; ++e) vc[p][e] = 0.f;
    }
    size_t o = (size_t)a * 2048 + j0;
#pragma unroll
    for (int p = 0; p < 4; ++p) {
      bf16x8 vh, vl;
#pragma unroll
      for (int e = 0; e < 8; ++e) {
        bf16 h = (bf16)vc[p][e];
        vh[e] = h;
        vl[e] = (bf16)(vc[p][e] - (float)h);
      }
      *(bf16x8*)(AphH + p * PA + o) = vh;
      *(bf16x8*)(AphL + p * PA + o) = vl;
    }
  } else if (bid < 3072) {
    int e = ((bid - 1024) * 256 + tid) * 8;
    int j = e >> 11, k = e & 2047;
    bf16x8 v;
    if (j < 2000 && k < 2000) {
      const float4* s = (const float4*)(K11 + (size_t)j * 2000 + k);
      float4 f0 = s[0], f1 = s[1];
      v[0] = (bf16)f0.x; v[1] = (bf16)f0.y; v[2] = (bf16)f0.z; v[3] = (bf16)f0.w;
      v[4] = (bf16)f1.x; v[5] = (bf16)f1.y; v[6] = (bf16)f1.z; v[7] = (bf16)f1.w;
    } else {
      for (int i = 0; i < 8; ++i) v[i] = (bf16)0.f;
    }
    *(bf16x8*)(Kbf + e) = v;
  } else {
    // K12^T -> hi/lo bf16 (transpose, padded)
    int b2 = bid - 3072;
    int j0 = (b2 & 31) * 64, z0 = (b2 >> 5) * 64;
    for (int e = tid; e < 4096; e += 256) {
      int r = e >> 6, c = e & 63;  // r = j row, c = z col
      t[r][c] = (j0 + r < 2000 && z0 + c < 2000)
                    ? K12[(size_t)(j0 + r) * 2000 + z0 + c] : 0.f;
    }
    __syncthreads();
#pragma unroll
    for (int it = 0; it < 2; ++it) {
      int idx = it * 256 + tid;
      int zr = idx >> 3, c8 = (idx & 7) * 8;
      bf16x8 vh, vl;
#pragma unroll
      for (int e = 0; e < 8; ++e) {
        float g = t[c8 + e][zr];
        bf16 h = (bf16)g;
        vh[e] = h;
        vl[e] = (bf16)(g - (float)h);
      }
      size_t ob = (size_t)(z0 + zr) * 2048 + j0 + c8;
      *(bf16x8*)(K12T + ob) = vh;
      *(bf16x8*)(K12TL + ob) = vl;
    }
  }
}

// --------------- k_gemm1: full-z gamma_X hi/lo (Neumann fused) --------------
__global__ __launch_bounds__(256, 2) void k_gemm1(
    const bf16* __restrict__ K12T, const bf16* __restrict__ K12TL,
    const bf16* __restrict__ Kbf, const float* __restrict__ ll,
    bf16* __restrict__ gxHi, bf16* __restrict__ gxLo) {
  __shared__ __align__(16) char smem[34816];
  bf16(*lds)[128][64] = (bf16(*)[128][64])smem;
  const int tid = threadIdx.x;
  int bm = blockIdx.x * 128;  // z-tile (global)
  int bn = blockIdx.y * 128;  // j-tile
  const int w = tid >> 6, ln = tid & 63;
  const int r8 = ln >> 3, c8 = (ln & 7) * 8;
  f32x4 acc[4][4];
#pragma unroll
  for (int i = 0; i < 4; i++)
#pragma unroll
    for (int j = 0; j < 4; j++) acc[i][j] = {0.f, 0.f, 0.f, 0.f};
  const int m0 = (w & 1) * 64, n0 = (w >> 1) * 64;
  const int fr = ln & 15, kq = (ln >> 4) * 8;
  for (int kt = 0; kt < 2048; kt += 64) {
#pragma unroll
    for (int q = 0; q < 4; ++q) {
      int row = (w * 4 + q) * 8 + r8;
      async16(K12T + (size_t)(bm + row) * 2048 + (kt + c8), &lds[0][row][c8]);
      async16(Kbf + (size_t)(bn + row) * 2048 + (kt + c8), &lds[1][row][c8]);
    }
    __syncthreads();
#pragma unroll
    for (int ks = 0; ks < 64; ks += 32) {
      bf16x8 a[4], b[4];
#pragma unroll
      for (int i = 0; i < 4; i++) {
        a[i] = *(const bf16x8*)&lds[0][m0 + i * 16 + fr][ks + kq];
        b[i] = *(const bf16x8*)&lds[1][n0 + i * 16 + fr][ks + kq];
      }
#pragma unroll
      for (int i = 0; i < 4; i++)
#pragma unroll
        for (int j = 0; j < 4; j++)
          acc[i][j] = __builtin_amdgcn_mfma_f32_16x16x32_bf16(
              a[i], b[j], acc[i][j], 0, 0, 0);
    }
    __syncthreads();
  }
  // epilogue: stage fp32 T1 per n-half; gx = (K12T(hi+lo) - T1*inv)*inv
  float inv = 1.f / (2000.f * __expf(ll[0]));
  float* ft = (float*)smem;  // [128][68]
  const int cr = (ln >> 4) * 4, cc = ln & 15;
  const int gtid = (tid & 7) * 8;
#pragma unroll
  for (int h = 0; h < 2; ++h) {
    if ((w >> 1) == h) {
#pragma unroll
      for (int i = 0; i < 4; i++)
#pragma unroll
        for (int j = 0; j < 4; j++)
#pragma unroll
          for (int r = 0; r < 4; r++)
            ft[(m0 + i * 16 + cr + r) * 68 + j * 16 + cc] = acc[i][j][r];
    }
    __syncthreads();
    int jbase = bn + h * 64 + gtid;
#pragma unroll
    for (int it = 0; it < 4; ++it) {
      int idx = it * 256 + tid;
      int m = idx >> 3;
      int zg = bm + m;
      size_t gb = (size_t)zg * 2048 + jbase;
      bf16x8 kh = *(const bf16x8*)(K12T + gb);
      bf16x8 klo = *(const bf16x8*)(K12TL + gb);
      bf16x8 vh, vl;
#pragma unroll
      for (int e = 0; e < 8; ++e) {
        float t1 = ft[m * 68 + gtid + e];
        float gx = ((float)kh[e] + (float)klo[e] - t1 * inv) * inv;
        bf16 hh = (bf16)gx;
        vh[e] = hh;
        vl[e] = (bf16)(gx - (float)hh);
      }
      *(bf16x8*)(gxHi + gb) = vh;
      *(bf16x8*)(gxLo + gb) = vl;
    }
    __syncthreads();
  }
}

// ------------- k_prep: elementwise B-planes (per z-chunk) -------------------
// Bt planes [18][ZC][2048]: p0/p1 gN hi/lo; p2-9 M_d*gMN^T; p10-17 X_d*gX^T
__global__ __launch_bounds__(256) void k_prep(
    const float* __restrict__ gN, const float* __restrict__ gMN,
    const float* __restrict__ Mm, const float* __restrict__ Xm,
    const bf16* __restrict__ gxHi, const bf16* __restrict__ gxLo,
    bf16* __restrict__ Bt, int zg0, int ZC) {
  const size_t PL = (size_t)ZC * 2048;
  int j0 = blockIdx.x * 64, zl0 = blockIdx.y * 64;
  int zg = zg0 + zl0;
  int tid = threadIdx.x;
  __shared__ float t[64][65];

  for (int e = tid; e < 4096; e += 256) {
    int r = e >> 6, c = e & 63;
    t[r][c] = (j0 + r < 2000 && zg + c < 2000)
                  ? gN[(size_t)(j0 + r) * 2000 + zg + c] : 0.f;
  }
  __syncthreads();
#pragma unroll
  for (int it = 0; it < 2; ++it) {
    int idx = it * 256 + tid;
    int zr = idx >> 3, c8 = (idx & 7) * 8;
    bf16x8 vh, vl;
#pragma unroll
    for (int e = 0; e < 8; ++e) {
      float g = t[c8 + e][zr];
      bf16 h = (bf16)g;
      vh[e] = h;
      vl[e] = (bf16)(g - (float)h);
    }
    size_t ob = (size_t)(zl0 + zr) * 2048 + j0 + c8;
    *(bf16x8*)(Bt + 0 * PL + ob) = vh;
    *(bf16x8*)(Bt + 1 * PL + ob) = vl;
  }
  __syncthreads();

  for (int e = tid; e < 4096; e += 256) {
    int r = e >> 6, c = e & 63;
    t[r][c] = (j0 + r < 2000 && zg + c < 2000)
                  ? gMN[(size_t)(j0 + r) * 2000 + zg + c] : 0.f;
  }
  __syncthreads();
  const float4* M4 = (const float4*)Mm;
  const float4* X4 = (const float4*)Xm;
#pragma unroll
  for (int it = 0; it < 2; ++it) {
    int idx = it * 256 + tid;
    int zr = idx >> 3, c8 = (idx & 7) * 8;
    float g[8], mrow[8][8];
#pragma unroll
    for (int e = 0; e < 8; ++e) {
      g[e] = t[c8 + e][zr];
      int jj = j0 + c8 + e;
      if (jj < 2000) {
        float4 ma = M4[jj * 2], mb = M4[jj * 2 + 1];
        mrow[e][0] = ma.x; mrow[e][1] = ma.y; mrow[e][2] = ma.z;
        mrow[e][3] = ma.w; mrow[e][4] = mb.x; mrow[e][5] = mb.y;
        mrow[e][6] = mb.z; mrow[e][7] = mb.w;
      } else {
#pragma unroll
        for (int d = 0; d < 8; ++d) mrow[e][d] = 0.f;
      }
    }
    size_t ob = (size_t)(zl0 + zr) * 2048 + j0 + c8;
#pragma unroll
    for (int d = 0; d < 8; ++d) {
      bf16x8 v;
#pragma unroll
      for (int e = 0; e < 8; ++e) v[e] = (bf16)(g[e] * mrow[e][d]);
      *(bf16x8*)(Bt + (size_t)(2 + d) * PL + ob) = v;
    }
  }

#pragma unroll
  for (int it = 0; it < 2; ++it) {
    int idx = it * 256 + tid;
    int zr = idx >> 3, c8 = (idx & 7) * 8;
    size_t gb = (size_t)(zg + zr) * 2048 + j0 + c8;
    bf16x8 vh = *(const bf16x8*)(gxHi + gb);
    bf16x8 vl = *(const bf16x8*)(gxLo + gb);
    float gx[8], xr[8][8];
#pragma unroll
    for (int e = 0; e < 8; ++e) {
      gx[e] = (float)vh[e] + (float)vl[e];
      int jj = j0 + c8 + e;
      if (jj < 2000) {
        float4 xa = X4[jj * 2], xb = X4[jj * 2 + 1];
        xr[e][0] = xa.x; xr[e][1] = xa.y; xr[e][2] = xa.z; xr[e][3] = xa.w;
        xr[e][4] = xb.x; xr[e][5] = xb.y; xr[e][6] = xb.z; xr[e][7] = xb.w;
      } else {
#pragma unroll
        for (int d = 0; d < 8; ++d) xr[e][d] = 0.f;
      }
    }
    size_t ob = (size_t)(zl0 + zr) * 2048 + j0 + c8;
#pragma unroll
    for (int d = 0; d < 8; ++d) {
      bf16x8 v;
#pragma unroll
      for (int e = 0; e < 8; ++e) v[e] = (bf16)(gx[e] * xr[e][d]);
      *(bf16x8*)(Bt + (size_t)(10 + d) * PL + ob) = v;
    }
  }
}

// --------------------- unified num+den GEMM dispatch ------------------------
__global__ __launch_bounds__(256, 2) void k_mm(
    const bf16* __restrict__ AphH, const bf16* __restrict__ AphL,
    const bf16* __restrict__ Bt, const bf16* __restrict__ gxHi,
    const bf16* __restrict__ gxLo, unsigned int* __restrict__ Cpk,
    float* __restrict__ den, int ZC, int zg0) {
  const size_t PA = (size_t)1024 * 2048;
  const size_t PL = (size_t)ZC * 2048;
  const size_t PC = (size_t)1024 * ZC;
  __shared__ __align__(16) bf16 smem[3 * 128 * 64];
  const int tid = threadIdx.x;
  const int w = tid >> 6, ln = tid & 63;
  const int fr = ln & 15, kq = (ln >> 4) * 8;
  const int cr = (ln >> 4) * 4, cc = ln & 15;
  const int zb = blockIdx.z;

  if (zb < 16) {
    // ---------------- num pair-plane (re,im packed) ----------------
    bf16(*lds)[128][64] = (bf16(*)[128][64])smem;
    const bf16* A0 = AphH + (size_t)(zb < 8 ? 0 : 2) * PA;
    const bf16* A1 = A0 + PA;
    const bf16* B = Bt + (size_t)(2 + zb) * PL;
    unsigned int* P = Cpk + (size_t)zb * PC;
    int bm = blockIdx.x * 128, bn = blockIdx.y * 128;
    const int r8 = ln >> 3, c8 = (ln & 7) * 8;

    f32x4 acc0[4][4], acc1[4][4];
#pragma unroll
    for (int i = 0; i < 4; i++)
#pragma unroll
      for (int j = 0; j < 4; j++) {
        acc0[i][j] = {0.f, 0.f, 0.f, 0.f};
        acc1[i][j] = {0.f, 0.f, 0.f, 0.f};
      }
    const int m0 = (w & 1) * 64, n0 = (w >> 1) * 64;

    for (int kt = 0; kt < 2048; kt += 64) {
#pragma unroll
      for (int q = 0; q < 4; ++q) {
        int row = (w * 4 + q) * 8 + r8;
        async16(A0 + (size_t)(bm + row) * 2048 + (kt + c8), &lds[0][row][c8]);
        async16(A1 + (size_t)(bm + row) * 2048 + (kt + c8), &lds[1][row][c8]);
        async16(B + (size_t)(bn + row) * 2048 + (kt + c8), &lds[2][row][c8]);
      }
      __syncthreads();
#pragma unroll
      for (int ks = 0; ks < 64; ks += 32) {
        bf16x8 a0[4], a1[4], b[4];
#pragma unroll
        for (int i = 0; i < 4; i++) {
          a0[i] = *(const bf16x8*)&lds[0][m0 + i * 16 + fr][ks + kq];
          a1[i] = *(const bf16x8*)&lds[1][m0 + i * 16 + fr][ks + kq];
          b[i] = *(const bf16x8*)&lds[2][n0 + i * 16 + fr][ks + kq];
        }
#pragma unroll
        for (int i = 0; i < 4; i++)
#pragma unroll
          for (int j = 0; j < 4; j++) {
            acc0[i][j] = __builtin_amdgcn_mfma_f32_16x16x32_bf16(
                a0[i], b[j], acc0[i][j], 0, 0, 0);
            acc1[i][j] = __builtin_amdgcn_mfma_f32_16x16x32_bf16(
                a1[i], b[j], acc1[i][j], 0, 0, 0);
          }
      }
      __syncthreads();
    }
#pragma unroll
    for (int i = 0; i < 4; i++)
#pragma unroll
      for (int j = 0; j < 4; j++)
#pragma unroll
        for (int r = 0; r < 4; r++) {
          union { bf16 h[2]; unsigned int u; } pk;
          pk.h[0] = (bf16)acc0[i][j][r];
          pk.h[1] = (bf16)acc1[i][j][r];
          P[(size_t)(bm + m0 + i * 16 + cr + r) * ZC +
            (bn + n0 + j * 16 + cc)] = pk.u;
        }
  } else {
    // ---------------- den tile (split-bf16, 128x64) ----------------
    bf16(*lds)[64] = (bf16(*)[64])smem;
    int nyTiles = ZC / 64;
    int den_idx = (zb - 16) * (ZC / 128) + blockIdx.y;
    int p = den_idx / nyTiles;  // 0 denN_re,1 denN_im,2 denX_re,3 denX_im
    int ny = den_idx % nyTiles;
    int side = p >> 1, trig = p & 1;
    const bf16* Ah = AphH + (size_t)(side * 2 + trig) * PA;
    const bf16* Al = AphL + (size_t)(side * 2 + trig) * PA;
    const bf16* Bh = side ? (gxHi + (size_t)zg0 * 2048) : (Bt + 0 * PL);
    const bf16* Bl = side ? (gxLo + (size_t)zg0 * 2048) : (Bt + 1 * PL);
    float* C = den + (size_t)p * PC;
    int bm = blockIdx.x * 128, bn = ny * 64;
    const int r32 = tid >> 3, c8 = (tid & 7) * 8;

    f32x4 acc[4][2];
#pragma unroll
    for (int i = 0; i < 4; i++)
#pragma unroll
      for (int j = 0; j < 2; j++) acc[i][j] = {0.f, 0.f, 0.f, 0.f};
    const int m0 = (w & 1) * 64, n0 = (w >> 1) * 32;

    for (int kt = 0; kt < 2048; kt += 64) {
#pragma unroll
      for (int q = 0; q < 4; ++q) {
        int row = q * 32 + r32;
        async16(Ah + (size_t)(bm + row) * 2048 + (kt + c8), &lds[row][c8]);
        async16(Al + (size_t)(bm + row) * 2048 + (kt + c8),
                &lds[128 + row][c8]);
      }
#pragma unroll
      for (int q = 0; q < 2; ++q) {
        int row = q * 32 + r32;
        async16(Bh + (size_t)(bn + row) * 2048 + (kt + c8),
                &lds[256 + row][c8]);
        async16(Bl + (size_t)(bn + row) * 2048 + (kt + c8),
                &lds[320 + row][c8]);
      }
      __syncthreads();
#pragma unroll
      for (int ks = 0; ks < 64; ks += 32) {
        bf16x8 ah[4], alo[4], bh[2], blo[2];
#pragma unroll
        for (int i = 0; i < 4; i++) {
          ah[i]  = *(const bf16x8*)&lds[m0 + i * 16 + fr][ks + kq];
          alo[i] = *(const bf16x8*)&lds[128 + m0 + i * 16 + fr][ks + kq];
        }
#pragma unroll
        for (int j = 0; j < 2; j++) {
          bh[j]  = *(const bf16x8*)&lds[256 + n0 + j * 16 + fr][ks + kq];
          blo[j] = *(const bf16x8*)&lds[320 + n0 + j * 16 + fr][ks + kq];
        }
#pragma unroll
        for (int i = 0; i < 4; i++)
#pragma unroll
          for (int j = 0; j < 2; j++) {
            acc[i][j] = __builtin_amdgcn_mfma_f32_16x16x32_bf16(
                alo[i], bh[j], acc[i][j], 0, 0, 0);
            acc[i][j] = __builtin_amdgcn_mfma_f32_16x16x32_bf16(
                ah[i], blo[j], acc[i][j], 0, 0, 0);
            acc[i][j] = __builtin_amdgcn_mfma_f32_16x16x32_bf16(
                ah[i], bh[j], acc[i][j], 0, 0, 0);
          }
      }
      __syncthreads();
    }
#pragma unroll
    for (int i = 0; i < 4; i++)
#pragma unroll
      for (int j = 0; j < 2; j++)
#pragma unroll
        for (int r = 0; r < 4; r++) {
          size_t idx = (size_t)(bm + m0 + i * 16 + cr + r) * ZC +
                       (bn + n0 + j * 16 + cc);
          C[idx] = acc[i][j][r];
        }
  }
}

// --------------------------- final reduction -------------------------------
__device__ __forceinline__ void load8p(const unsigned int* p, float* re,
                                       float* im) {
  uint4 u0 = ((const uint4*)p)[0], u1 = ((const uint4*)p)[1];
  re[0] = __uint_as_float(u0.x << 16); im[0] = __uint_as_float(u0.x & 0xffff0000u);
  re[1] = __uint_as_float(u0.y << 16); im[1] = __uint_as_float(u0.y & 0xffff0000u);
  re[2] = __uint_as_float(u0.z << 16); im[2] = __uint_as_float(u0.z & 0xffff0000u);
  re[3] = __uint_as_float(u0.w << 16); im[3] = __uint_as_float(u0.w & 0xffff0000u);
  re[4] = __uint_as_float(u1.x << 16); im[4] = __uint_as_float(u1.x & 0xffff0000u);
  re[5] = __uint_as_float(u1.y << 16); im[5] = __uint_as_float(u1.y & 0xffff0000u);
  re[6] = __uint_as_float(u1.z << 16); im[6] = __uint_as_float(u1.z & 0xffff0000u);
  re[7] = __uint_as_float(u1.w << 16); im[7] = __uint_as_float(u1.w & 0xffff0000u);
}
__device__ __forceinline__ void load8d(const float* p, float* o) {
  float4 f0 = ((const float4*)p)[0], f1 = ((const float4*)p)[1];
  o[0] = f0.x; o[1] = f0.y; o[2] = f0.z; o[3] = f0.w;
  o[4] = f1.x; o[5] = f1.y; o[6] = f1.z; o[7] = f1.w;
}

__global__ __launch_bounds__(256) void k_reduce(
    const unsigned int* __restrict__ Cpk, const float* __restrict__ den,
    float* __restrict__ out, int ZC, int zg0) {
  const size_t PS = (size_t)1024 * ZC;
  int tid = threadIdx.x;
  int a = blockIdx.x * 2 + (tid >> 7);
  int zt = tid & 127;
  float acc = 0.f;
  for (int z = zt * 8; z < ZC; z += 1024) {
    if (zg0 + z >= 2000) break;
    size_t base = (size_t)a * ZC + z;
    float mdr[8], mdi[8], xdr[8], xdi[8], im[8], ix[8];
    load8d(den + 0 * PS + base, mdr);
    load8d(den + 1 * PS + base, mdi);
    load8d(den + 2 * PS + base, xdr);
    load8d(den + 3 * PS + base, xdi);
#pragma unroll
    for (int e = 0; e < 8; ++e) {
      im[e] = 1.f / (mdr[e] * mdr[e] + mdi[e] * mdi[e]);
      ix[e] = 1.f / (xdr[e] * xdr[e] + xdi[e] * xdi[e]);
    }
#pragma unroll
    for (int d = 0; d < 8; ++d) {
      float ar[8], ai[8], br[8], bi[8];
      load8p(Cpk + (size_t)d * PS + base, ar, ai);
      load8p(Cpk + (size_t)(8 + d) * PS + base, br, bi);
#pragma unroll
      for (int e = 0; e < 8; ++e) {
        float r1 = (ar[e] * mdr[e] + ai[e] * mdi[e]) * im[e];
        float i1 = (ai[e] * mdr[e] - ar[e] * mdi[e]) * im[e];
        float r2 = (br[e] * xdr[e] + bi[e] * xdi[e]) * ix[e];
        float i2 = (bi[e] * xdr[e] - br[e] * xdi[e]) * ix[e];
        float dr = r1 - r2, di = i1 - i2;
        acc += dr * dr + di * di;
      }
    }
  }
  for (int off = 32; off; off >>= 1) acc += __shfl_down(acc, off, 64);
  __shared__ float red[4];
  if (!(tid & 63)) red[tid >> 6] = acc;
  __syncthreads();
  if (!tid)
    atomicAdd(out,
              (red[0] + red[1] + red[2] + red[3]) * (1.f / 2000000.f));
}

// ============================================================================
extern "C" void kernel_launch(void* const* d_in, const int* in_sizes, int n_in,
                              void* d_out, int out_size, void* d_ws,
                              size_t ws_size, hipStream_t stream) {
  const float* Mm  = (const float*)d_in[0];
  const float* Nm  = (const float*)d_in[1];
  const float* Xm  = (const float*)d_in[2];
  const float* ll  = (const float*)d_in[3];
  const float* K11 = (const float*)d_in[4];
  const float* K12 = (const float*)d_in[5];
  const float* gMN = (const float*)d_in[6];
  const float* gN  = (const float*)d_in[7];
  const float* al  = (const float*)d_in[8];

  char* ws = (char*)d_ws;
  const size_t MB = 1024 * 1024;
  bf16* AphH = (bf16*)(ws);             // 16 MB
  bf16* AphL = (bf16*)(ws + 16 * MB);   // 16 MB
  bf16* gxHi = (bf16*)(ws + 32 * MB);   // 8 MB [2048][2048]
  bf16* gxLo = (bf16*)(ws + 40 * MB);   // 8 MB
  char* chunkRgn = ws + 48 * MB;
  // transient (dead after k_gemm1), overlaid on chunk region:
  bf16* Kbf   = (bf16*)(chunkRgn);            // 8 MB
  bf16* K12T  = (bf16*)(chunkRgn + 8 * MB);   // 8 MB
  bf16* K12TL = (bf16*)(chunkRgn + 16 * MB);  // 8 MB

  // chunk: Bt 18 planes (73728*ZC) | den fp32 (16384*ZC) | Cpk (65536*ZC)
  size_t avail = (ws_size > 48 * MB) ? ws_size - 48 * MB : 0;
  int ZC = 2048;
  while (ZC > 128 && (size_t)155648 * ZC > avail) ZC >>= 1;
  int NC = 2048 / ZC;
  bf16* Btc = (bf16*)(chunkRgn);
  float* denc = (float*)(chunkRgn + (size_t)73728 * ZC);
  unsigned int* Cpkc = (unsigned int*)(chunkRgn + (size_t)90112 * ZC);

  k_pre<<<dim3(4096), dim3(256), 0, stream>>>(al, Nm, Xm, K11, K12, AphH,
                                              AphL, Kbf, K12T, K12TL,
                                              (float*)d_out);
  k_gemm1<<<dim3(16, 16), dim3(256), 0, stream>>>(K12T, K12TL, Kbf, ll, gxHi,
                                                  gxLo);
  for (int c = 0; c < NC; ++c) {
    int zg0 = c * ZC;
    k_prep<<<dim3(32, ZC / 64), dim3(256), 0, stream>>>(gN, gMN, Mm, Xm, gxHi,
                                                        gxLo, Btc, zg0, ZC);
    k_mm<<<dim3(8, ZC / 128, 24), dim3(256), 0, stream>>>(
        AphH, AphL, Btc, gxHi, gxLo, Cpkc, denc, ZC, zg0);
    k_reduce<<<dim3(500), dim3(256), 0, stream>>>(Cpkc, denc, (float*)d_out,
                                                  ZC, zg0);
  }
  (void)in_sizes; (void)n_in; (void)out_size;
}